// Round 1
// baseline (325.011 us; speedup 1.0000x reference)
//
#include <hip/hip_runtime.h>
#include <hip/hip_bf16.h>
#include <stdint.h>

// Problem constants: B=64, L=96, C=32, H=256, NL=2, K=3, TAU=2, VTH=1
// n = b*32 + c indexes the B*C=2048 "rows"; layer width H=256.

using short8  = __attribute__((ext_vector_type(8))) short;
using floatx4 = __attribute__((ext_vector_type(4))) float;

__device__ __forceinline__ unsigned short f2bf(float f) {
    unsigned int u = __float_as_uint(f);
    unsigned int r = u + 0x7fffu + ((u >> 16) & 1u);   // RNE
    return (unsigned short)(r >> 16);
}
__device__ __forceinline__ float bf2f(unsigned short h) {
    return __uint_as_float(((unsigned int)h) << 16);
}

// ---------------------------------------------------------------------------
// prep: per output-neuron o (256 blocks x 64 threads)
//  - W[o][k]  = sum_i w0[o,i]*w_enc[i,k]   (fp64)
//  - C0[o]    = sum_i b_enc[i]*w0[o,i] + b_rnn[0][o]  (fp64)
//  - split-3 bf16 decomposition of w1 row o into Bw[o][0..767]
//    layout: Bw[o][i]=hi, Bw[o][256+i]=mid, Bw[o][512+i]=lo
// ---------------------------------------------------------------------------
__global__ void prep_kernel(const float* __restrict__ w_enc,
                            const float* __restrict__ b_enc,
                            const float* __restrict__ w_rnn,
                            const float* __restrict__ b_rnn,
                            double* __restrict__ Wd,
                            double* __restrict__ C0d,
                            unsigned short* __restrict__ Bw)
{
    const int o = blockIdx.x;
    const int lane = threadIdx.x;   // 64 threads
    const float4 w0v = *(const float4*)(w_rnn + (size_t)o * 256 + lane * 4);
    double a0 = 0.0, a1 = 0.0, a2 = 0.0, ab = 0.0;
#pragma unroll
    for (int e = 0; e < 4; ++e) {
        const int i = lane * 4 + e;
        const double wv = (double)(((const float*)&w0v)[e]);
        a0 += wv * (double)w_enc[i * 3 + 0];
        a1 += wv * (double)w_enc[i * 3 + 1];
        a2 += wv * (double)w_enc[i * 3 + 2];
        ab += wv * (double)b_enc[i];
    }
    for (int off = 32; off > 0; off >>= 1) {
        a0 += __shfl_down(a0, off, 64);
        a1 += __shfl_down(a1, off, 64);
        a2 += __shfl_down(a2, off, 64);
        ab += __shfl_down(ab, off, 64);
    }
    if (lane == 0) {
        Wd[o * 3 + 0] = a0;
        Wd[o * 3 + 1] = a1;
        Wd[o * 3 + 2] = a2;
        C0d[o] = ab + (double)b_rnn[o];
    }
    // split-3 of w1 (layer-1 weights), exact: f == hi+mid+lo + r, |r| <= 2^-27|f|
    const float4 w1v = *(const float4*)(w_rnn + 65536 + (size_t)o * 256 + lane * 4);
    ushort4 hi, mi, lo;
#pragma unroll
    for (int e = 0; e < 4; ++e) {
        float f = ((const float*)&w1v)[e];
        unsigned short h = f2bf(f);
        float r1 = f - bf2f(h);          // Sterbenz-exact
        unsigned short mm = f2bf(r1);
        float r2 = r1 - bf2f(mm);        // exact
        unsigned short ll = f2bf(r2);
        ((unsigned short*)&hi)[e] = h;
        ((unsigned short*)&mi)[e] = mm;
        ((unsigned short*)&lo)[e] = ll;
    }
    *(ushort4*)(Bw + (size_t)o * 768 + lane * 4)       = hi;
    *(ushort4*)(Bw + (size_t)o * 768 + 256 + lane * 4) = mi;
    *(ushort4*)(Bw + (size_t)o * 768 + 512 + lane * 4) = lo;
}

// ---------------------------------------------------------------------------
// enc: layer-0 full scan. 2048 blocks (one per row n) x 256 threads (one per
// neuron o). cur0 in fp64 (correctly rounded), membrane chain in exact
// reference fp32 op order. Spikes emitted as 64-bit ballots:
// s0b u64 index = (t*2048 + n)*4 + wave  (bit j of wave w  <->  i = 64w+j)
// ---------------------------------------------------------------------------
__global__ void enc_kernel(const float* __restrict__ inputs,
                           const double* __restrict__ Wd,
                           const double* __restrict__ C0d,
                           unsigned long long* __restrict__ s0b)
{
    const int n = blockIdx.x;
    const int tidx = threadIdx.x;
    const int b = n >> 5, c = n & 31;
    __shared__ float xr[98];                  // zero-padded [x[-1], x[0..95], x[96]]
    if (tidx < 96)       xr[tidx + 1] = inputs[((size_t)b * 96 + tidx) * 32 + c];
    else if (tidx == 96) xr[0]  = 0.0f;
    else if (tidx == 97) xr[97] = 0.0f;
    __syncthreads();
    const double W0 = Wd[tidx * 3], W1 = Wd[tidx * 3 + 1], W2 = Wd[tidx * 3 + 2];
    const double c0 = C0d[tidx];
    const int wid = tidx >> 6, lane = tidx & 63;
    float v = 0.0f;
    for (int t = 0; t < 96; ++t) {
        float cur = (float)((double)xr[t] * W0 + (double)xr[t + 1] * W1 +
                            (double)xr[t + 2] * W2 + c0);
        float vv = v + (cur - v) * 0.5f;      // v + (cur-v)/TAU, /2 exact
        int sp = (vv - 1.0f) >= 0.0f;         // exact near threshold (Sterbenz)
        v = sp ? 0.0f : vv;                   // hard reset
        unsigned long long bal = __ballot(sp);
        if (lane == 0) s0b[((size_t)t * 2048 + n) * 4 + wid] = bal;
    }
}

// ---------------------------------------------------------------------------
// rnn: layer-1. Blocks independent: grid 256 = 32 n-blocks x 8 o-blocks.
// Block = 4 waves; wave w owns rows [nb*64 + w*16, +16), cols [ob*32, +32).
// B (w1 split-3, K=768) cached in VGPRs (192 regs) -> __launch_bounds__(256,1).
// Per t: load 32B spike-row masks (prefetched one step ahead), expand 8 unique
// A-frags (bits->bf16), 48 MFMAs (24 ksteps x 2 subtiles), exact fp32 membrane
// update in registers, store spikes straight to out0 (and out1 at t=95).
// MFMA A layout: A[m=lane&15][k=(lane>>4)*8+j]; B[k][n=lane&15];
// C/D: col=lane&15, row=(lane>>4)*4+reg.
// ---------------------------------------------------------------------------
__global__ __launch_bounds__(256, 1) void rnn_kernel(
    const unsigned char* __restrict__ s0b,
    const unsigned short* __restrict__ Bw,
    const float* __restrict__ b_rnn,
    float* __restrict__ out0,
    float* __restrict__ out1)
{
    const int tid  = threadIdx.x;
    const int wid  = tid >> 6, lane = tid & 63;
    const int m    = lane & 15, g = lane >> 4;
    const int nblk = blockIdx.x >> 3, oblk = blockIdx.x & 7;
    const int nw   = nblk * 64 + wid * 16;
    const int o0   = oblk * 32;

    // --- preload B fragments (loop-invariant over t) ---
    short8 bfrag[24][2];
#pragma unroll
    for (int ks = 0; ks < 24; ++ks)
#pragma unroll
        for (int sub = 0; sub < 2; ++sub) {
            const unsigned short* p =
                Bw + (size_t)(o0 + sub * 16 + m) * 768 + ks * 32 + g * 8;
            bfrag[ks][sub] = *(const short8*)p;
        }
    const float bias0 = b_rnn[256 + o0 + m];
    const float bias1 = b_rnn[256 + o0 + 16 + m];

    floatx4 v0 = {0.f, 0.f, 0.f, 0.f};
    floatx4 v1 = {0.f, 0.f, 0.f, 0.f};

    const int rowm = nw + m;                      // A-operand row for this lane
    const int g8 = g * 8;
    uint4 ma = *(const uint4*)(s0b + ((size_t)rowm) * 32);
    uint4 mb = *(const uint4*)(s0b + ((size_t)rowm) * 32 + 16);

    for (int t = 0; t < 96; ++t) {
        // prefetch next timestep's masks
        uint4 pna = ma, pnb = mb;
        if (t < 95) {
            const unsigned char* q = s0b + ((size_t)(t + 1) * 2048 + rowm) * 32;
            pna = *(const uint4*)q;
            pnb = *(const uint4*)(q + 16);
        }
        // expand 8 unique A-fragments (shared by hi/mid/lo k-ranges)
        unsigned int w32[8] = {ma.x, ma.y, ma.z, ma.w, mb.x, mb.y, mb.z, mb.w};
        short8 af[8];
#pragma unroll
        for (int ku = 0; ku < 8; ++ku) {
            unsigned int bits = (w32[ku] >> g8) & 0xffu;
            short8 a;
#pragma unroll
            for (int j = 0; j < 8; ++j)
                a[j] = (short)(((bits >> j) & 1u) * 0x3F80u);  // bf16 1.0 / 0.0
            af[ku] = a;
        }
        // GEMM: cur1 tile = spikes @ (w1_hi; w1_mid; w1_lo)
        floatx4 acc0 = {0.f, 0.f, 0.f, 0.f};
        floatx4 acc1 = {0.f, 0.f, 0.f, 0.f};
#pragma unroll
        for (int ks = 0; ks < 24; ++ks) {
            acc0 = __builtin_amdgcn_mfma_f32_16x16x32_bf16(af[ks & 7], bfrag[ks][0], acc0, 0, 0, 0);
            acc1 = __builtin_amdgcn_mfma_f32_16x16x32_bf16(af[ks & 7], bfrag[ks][1], acc1, 0, 0, 0);
        }
        // membrane update (exact reference fp32 op order) + spike store
#pragma unroll
        for (int r = 0; r < 4; ++r) {
            const int row = nw + g * 4 + r;       // C/D row for this lane/reg
            const int bb = row >> 5, cc = row & 31;
            const size_t obase = ((size_t)bb * 96 + t) * 8192 + (size_t)cc * 256;
            {
                float cur = acc0[r] + bias0;
                float vv = v0[r];
                vv = vv + (cur - vv) * 0.5f;
                float s = ((vv - 1.0f) >= 0.0f) ? 1.0f : 0.0f;
                v0[r] = vv * (1.0f - s);
                out0[obase + o0 + m] = s;
                if (t == 95) out1[(size_t)bb * 8192 + (size_t)cc * 256 + o0 + m] = s;
            }
            {
                float cur = acc1[r] + bias1;
                float vv = v1[r];
                vv = vv + (cur - vv) * 0.5f;
                float s = ((vv - 1.0f) >= 0.0f) ? 1.0f : 0.0f;
                v1[r] = vv * (1.0f - s);
                out0[obase + o0 + 16 + m] = s;
                if (t == 95) out1[(size_t)bb * 8192 + (size_t)cc * 256 + o0 + 16 + m] = s;
            }
        }
        ma = pna; mb = pnb;
    }
}

// ---------------------------------------------------------------------------
extern "C" void kernel_launch(void* const* d_in, const int* in_sizes, int n_in,
                              void* d_out, int out_size, void* d_ws, size_t ws_size,
                              hipStream_t stream) {
    const float* inputs = (const float*)d_in[0];   // [64,96,32]
    const float* w_enc  = (const float*)d_in[1];   // [256,1,3]
    const float* b_enc  = (const float*)d_in[2];   // [256]
    const float* w_rnn  = (const float*)d_in[3];   // [2,256,256]
    const float* b_rnn  = (const float*)d_in[4];   // [2,256]

    float* out0 = (float*)d_out;                       // [64,96,8192]
    float* out1 = out0 + (size_t)64 * 96 * 8192;       // [64,8192]

    char* ws = (char*)d_ws;
    double*         Wd  = (double*)(ws);               //  768 doubles  [0,6144)
    double*         C0d = (double*)(ws + 6144);        //  256 doubles  [6144,8192)
    unsigned short* Bw  = (unsigned short*)(ws + 8192);// 256*768 u16   [8192,401408)
    char*           s0b = ws + 401408;                 // 6291456 bytes of spike bits

    prep_kernel<<<256, 64, 0, stream>>>(w_enc, b_enc, w_rnn, b_rnn, Wd, C0d, Bw);
    enc_kernel<<<2048, 256, 0, stream>>>(inputs, Wd, C0d, (unsigned long long*)s0b);
    rnn_kernel<<<256, 256, 0, stream>>>((const unsigned char*)s0b, Bw, b_rnn, out0, out1);
}

// Round 2
// 271.179 us; speedup vs baseline: 1.1985x; 1.1985x over previous
//
#include <hip/hip_runtime.h>
#include <hip/hip_bf16.h>
#include <stdint.h>

// Problem constants: B=64, L=96, C=32, H=256, NL=2, K=3, TAU=2, VTH=1
// n = b*32 + c indexes the B*C=2048 "rows"; layer width H=256.

using short8  = __attribute__((ext_vector_type(8))) short;
using floatx4 = __attribute__((ext_vector_type(4))) float;

__device__ __forceinline__ unsigned short f2bf(float f) {
    unsigned int u = __float_as_uint(f);
    unsigned int r = u + 0x7fffu + ((u >> 16) & 1u);   // RNE
    return (unsigned short)(r >> 16);
}
__device__ __forceinline__ float bf2f(unsigned short h) {
    return __uint_as_float(((unsigned int)h) << 16);
}

// byte (8 spike bits) -> 8 bf16 halfwords (0x3F80 / 0x0000), 14 VALU ops:
// mul-spread nibble to 0/1 bytes, v_perm to halfword positions, *0x3F80.
__device__ __forceinline__ uint4 expand8(unsigned int byte) {
    unsigned int lo = ((byte & 0xFu) * 0x00204081u) & 0x01010101u;  // bytes=[b3,b2,b1,b0]
    unsigned int hi = (((byte >> 4) & 0xFu) * 0x00204081u) & 0x01010101u;
    uint4 d;
    // perm(a=0, b=v, sel): sel 0..3 -> b bytes, 4..7 -> a bytes (=0)
    d.x = __builtin_amdgcn_perm(0u, lo, 0x04010400u) * 0x3F80u;  // bits 0,1
    d.y = __builtin_amdgcn_perm(0u, lo, 0x04030402u) * 0x3F80u;  // bits 2,3
    d.z = __builtin_amdgcn_perm(0u, hi, 0x04010400u) * 0x3F80u;  // bits 4,5
    d.w = __builtin_amdgcn_perm(0u, hi, 0x04030402u) * 0x3F80u;  // bits 6,7
    return d;
}

// ---------------------------------------------------------------------------
// prep: per output-neuron o (256 blocks x 64 threads)
//  - W[o][k]  = sum_i w0[o,i]*w_enc[i,k]   (fp64)
//  - C0[o]    = sum_i b_enc[i]*w0[o,i] + b_rnn[0][o]  (fp64)
//  - split-3 bf16 decomposition of w1 row o into Bw[o][0..767]
// ---------------------------------------------------------------------------
__global__ void prep_kernel(const float* __restrict__ w_enc,
                            const float* __restrict__ b_enc,
                            const float* __restrict__ w_rnn,
                            const float* __restrict__ b_rnn,
                            double* __restrict__ Wd,
                            double* __restrict__ C0d,
                            unsigned short* __restrict__ Bw)
{
    const int o = blockIdx.x;
    const int lane = threadIdx.x;   // 64 threads
    const float4 w0v = *(const float4*)(w_rnn + (size_t)o * 256 + lane * 4);
    double a0 = 0.0, a1 = 0.0, a2 = 0.0, ab = 0.0;
#pragma unroll
    for (int e = 0; e < 4; ++e) {
        const int i = lane * 4 + e;
        const double wv = (double)(((const float*)&w0v)[e]);
        a0 += wv * (double)w_enc[i * 3 + 0];
        a1 += wv * (double)w_enc[i * 3 + 1];
        a2 += wv * (double)w_enc[i * 3 + 2];
        ab += wv * (double)b_enc[i];
    }
    for (int off = 32; off > 0; off >>= 1) {
        a0 += __shfl_down(a0, off, 64);
        a1 += __shfl_down(a1, off, 64);
        a2 += __shfl_down(a2, off, 64);
        ab += __shfl_down(ab, off, 64);
    }
    if (lane == 0) {
        Wd[o * 3 + 0] = a0;
        Wd[o * 3 + 1] = a1;
        Wd[o * 3 + 2] = a2;
        C0d[o] = ab + (double)b_rnn[o];
    }
    // split-3 of w1, exact: f == hi+mid+lo + r, |r| <= 2^-27 |f|
    const float4 w1v = *(const float4*)(w_rnn + 65536 + (size_t)o * 256 + lane * 4);
    ushort4 hi, mi, lo;
#pragma unroll
    for (int e = 0; e < 4; ++e) {
        float f = ((const float*)&w1v)[e];
        unsigned short h = f2bf(f);
        float r1 = f - bf2f(h);
        unsigned short mm = f2bf(r1);
        float r2 = r1 - bf2f(mm);
        unsigned short ll = f2bf(r2);
        ((unsigned short*)&hi)[e] = h;
        ((unsigned short*)&mi)[e] = mm;
        ((unsigned short*)&lo)[e] = ll;
    }
    *(ushort4*)(Bw + (size_t)o * 768 + lane * 4)       = hi;
    *(ushort4*)(Bw + (size_t)o * 768 + 256 + lane * 4) = mi;
    *(ushort4*)(Bw + (size_t)o * 768 + 512 + lane * 4) = lo;
}

// ---------------------------------------------------------------------------
// enc: layer-0 full scan. 2048 blocks x 256 threads. cur0 in fp64 (correctly
// rounded), membrane chain in exact reference fp32 op order. Spikes as
// ballots: s0b u64 index = (t*2048 + n)*4 + wave  (bit j <-> neuron 64w+j)
// ---------------------------------------------------------------------------
__global__ void enc_kernel(const float* __restrict__ inputs,
                           const double* __restrict__ Wd,
                           const double* __restrict__ C0d,
                           unsigned long long* __restrict__ s0b)
{
    const int n = blockIdx.x;
    const int tidx = threadIdx.x;
    const int b = n >> 5, c = n & 31;
    __shared__ float xr[98];
    if (tidx < 96)       xr[tidx + 1] = inputs[((size_t)b * 96 + tidx) * 32 + c];
    else if (tidx == 96) xr[0]  = 0.0f;
    else if (tidx == 97) xr[97] = 0.0f;
    __syncthreads();
    const double W0 = Wd[tidx * 3], W1 = Wd[tidx * 3 + 1], W2 = Wd[tidx * 3 + 2];
    const double c0 = C0d[tidx];
    const int wid = tidx >> 6, lane = tidx & 63;
    float v = 0.0f;
    for (int t = 0; t < 96; ++t) {
        float cur = (float)((double)xr[t] * W0 + (double)xr[t + 1] * W1 +
                            (double)xr[t + 2] * W2 + c0);
        float vv = v + (cur - v) * 0.5f;
        int sp = (vv - 1.0f) >= 0.0f;
        v = sp ? 0.0f : vv;
        unsigned long long bal = __ballot(sp);
        if (lane == 0) s0b[((size_t)t * 2048 + n) * 4 + wid] = bal;
    }
}

// ---------------------------------------------------------------------------
// rnn: layer-1. grid 512 = 128 row-tiles x 4 col-groups; block = 4 waves,
// 16 rows x 64 cols; wave w owns cols [cg*64 + w*16, +16) (1 subtile,
// 24 MFMAs/t over K=768 split-3; B frags = 96 VGPRs, loop-invariant).
// A-fragments (bit->bf16 expansion of the 16 spike rows) are SHARED across
// the 4 waves via double-buffered LDS: wave w expands frags {2w, 2w+1} of
// t+1 each iteration (masks prefetched 2 steps ahead), one barrier per t.
// MFMA A layout: A[m=lane&15][k=(lane>>4)*8+j]; C/D: col=lane&15,
// row=(lane>>4)*4+reg. Membrane update in exact reference fp32 op order.
// ---------------------------------------------------------------------------
__global__ __launch_bounds__(256, 2) void rnn_kernel(
    const unsigned char* __restrict__ s0b,
    const unsigned short* __restrict__ Bw,
    const float* __restrict__ b_rnn,
    float* __restrict__ out0,
    float* __restrict__ out1)
{
    const int tid  = threadIdx.x;
    const int wid  = tid >> 6, lane = tid & 63;
    const int m    = lane & 15, g = lane >> 4;
    const int g8   = g * 8;
    const int rt   = blockIdx.x >> 2, cg = blockIdx.x & 3;
    const int nw   = rt * 16;                 // block's 16 rows
    const int o0   = cg * 64 + wid * 16;      // this wave's 16 cols

    __shared__ unsigned char ebuf[2][8192];   // 8 frags x 1KB, double-buffered

    // --- B fragments (loop-invariant): 24 ksteps x 4 VGPRs = 96 VGPRs ---
    short8 bfrag[24];
#pragma unroll
    for (int ks = 0; ks < 24; ++ks)
        bfrag[ks] = *(const short8*)(Bw + (size_t)(o0 + m) * 768 + ks * 32 + g8);
    const float bias = b_rnn[256 + o0 + m];

    // --- per-lane output base pointers (C/D row = nw + g*4 + r) ---
    float* pr[4];
    int    row_r[4];
#pragma unroll
    for (int r = 0; r < 4; ++r) {
        const int row = nw + g * 4 + r;
        row_r[r] = row;
        pr[r] = out0 + ((size_t)(row >> 5) * 96) * 8192 + (size_t)(row & 31) * 256
                     + o0 + m;
    }

    // --- mask loader: producer lane handles row nw + m, dwords [2w, 2w+1] ---
    const unsigned char* mbase = s0b + ((size_t)(nw + m)) * 32 + wid * 8;
    #define LOADM(T) (*(const uint2*)(mbase + (size_t)(T) * 65536))

    // preamble: expand t=0 into ebuf[0]; fetch masks for t=1
    {
        uint2 m0 = LOADM(0);
        *(uint4*)(ebuf[0] + (2 * wid) * 1024 + lane * 16)     = expand8((m0.x >> g8) & 0xFFu);
        *(uint4*)(ebuf[0] + (2 * wid + 1) * 1024 + lane * 16) = expand8((m0.y >> g8) & 0xFFu);
    }
    uint2 mB = LOADM(1);

    floatx4 v = {0.f, 0.f, 0.f, 0.f};

    for (int t = 0; t < 96; ++t) {
        const int p = t & 1;
        __syncthreads();                       // ebuf[p] ready; prior reads of ebuf[1-p] done
        uint2 mC = LOADM(t + 2 < 96 ? t + 2 : 95);   // prefetch (latency-hidden)

        // consume A fragments of timestep t
        short8 af[8];
#pragma unroll
        for (int f = 0; f < 8; ++f)
            af[f] = *(const short8*)(ebuf[p] + f * 1024 + lane * 16);

        // produce A fragments of timestep t+1 into ebuf[1-p]
        if (t < 95) {
            *(uint4*)(ebuf[1 - p] + (2 * wid) * 1024 + lane * 16)     = expand8((mB.x >> g8) & 0xFFu);
            *(uint4*)(ebuf[1 - p] + (2 * wid + 1) * 1024 + lane * 16) = expand8((mB.y >> g8) & 0xFFu);
        }

        // GEMM: cur1 tile = spikes @ (w1_hi; w1_mid; w1_lo)
        floatx4 acc = {0.f, 0.f, 0.f, 0.f};
#pragma unroll
        for (int ks = 0; ks < 24; ++ks)
            acc = __builtin_amdgcn_mfma_f32_16x16x32_bf16(af[ks & 7], bfrag[ks], acc, 0, 0, 0);

        // membrane update (exact reference fp32 op order) + spike store
#pragma unroll
        for (int r = 0; r < 4; ++r) {
            float cur = acc[r] + bias;
            float vv = v[r];
            vv = vv + (cur - vv) * 0.5f;
            float s = ((vv - 1.0f) >= 0.0f) ? 1.0f : 0.0f;
            v[r] = vv * (1.0f - s);
            pr[r][(size_t)t * 8192] = s;
            if (t == 95) out1[(size_t)row_r[r] * 256 + o0 + m] = s;
        }
        mB = mC;
    }
    #undef LOADM
}

// ---------------------------------------------------------------------------
extern "C" void kernel_launch(void* const* d_in, const int* in_sizes, int n_in,
                              void* d_out, int out_size, void* d_ws, size_t ws_size,
                              hipStream_t stream) {
    const float* inputs = (const float*)d_in[0];   // [64,96,32]
    const float* w_enc  = (const float*)d_in[1];   // [256,1,3]
    const float* b_enc  = (const float*)d_in[2];   // [256]
    const float* w_rnn  = (const float*)d_in[3];   // [2,256,256]
    const float* b_rnn  = (const float*)d_in[4];   // [2,256]

    float* out0 = (float*)d_out;                       // [64,96,8192]
    float* out1 = out0 + (size_t)64 * 96 * 8192;       // [64,8192]

    char* ws = (char*)d_ws;
    double*         Wd  = (double*)(ws);               //  768 doubles  [0,6144)
    double*         C0d = (double*)(ws + 6144);        //  256 doubles  [6144,8192)
    unsigned short* Bw  = (unsigned short*)(ws + 8192);// 256*768 u16   [8192,401408)
    char*           s0b = ws + 401408;                 // 6291456 bytes of spike bits

    prep_kernel<<<256, 64, 0, stream>>>(w_enc, b_enc, w_rnn, b_rnn, Wd, C0d, Bw);
    enc_kernel<<<2048, 256, 0, stream>>>(inputs, Wd, C0d, (unsigned long long*)s0b);
    rnn_kernel<<<512, 256, 0, stream>>>((const unsigned char*)s0b, Bw, b_rnn, out0, out1);
}

// Round 3
// 271.027 us; speedup vs baseline: 1.1992x; 1.0006x over previous
//
#include <hip/hip_runtime.h>
#include <hip/hip_bf16.h>
#include <stdint.h>

// Problem constants: B=64, L=96, C=32, H=256, NL=2, K=3, TAU=2, VTH=1
// n = b*32 + c indexes the B*C=2048 "rows"; layer width H=256.

using short8  = __attribute__((ext_vector_type(8))) short;
using floatx4 = __attribute__((ext_vector_type(4))) float;

__device__ __forceinline__ unsigned short f2bf(float f) {
    unsigned int u = __float_as_uint(f);
    unsigned int r = u + 0x7fffu + ((u >> 16) & 1u);   // RNE
    return (unsigned short)(r >> 16);
}
__device__ __forceinline__ float bf2f(unsigned short h) {
    return __uint_as_float(((unsigned int)h) << 16);
}

// byte (8 spike bits) -> 8 bf16 halfwords (0x3F80 / 0x0000), 14 VALU ops.
__device__ __forceinline__ uint4 expand8(unsigned int byte) {
    unsigned int lo = ((byte & 0xFu) * 0x00204081u) & 0x01010101u;
    unsigned int hi = (((byte >> 4) & 0xFu) * 0x00204081u) & 0x01010101u;
    uint4 d;
    d.x = __builtin_amdgcn_perm(0u, lo, 0x04010400u) * 0x3F80u;  // bits 0,1
    d.y = __builtin_amdgcn_perm(0u, lo, 0x04030402u) * 0x3F80u;  // bits 2,3
    d.z = __builtin_amdgcn_perm(0u, hi, 0x04010400u) * 0x3F80u;  // bits 4,5
    d.w = __builtin_amdgcn_perm(0u, hi, 0x04030402u) * 0x3F80u;  // bits 6,7
    return d;
}

// ---------------------------------------------------------------------------
// prep: per output-neuron o (256 blocks x 64 threads)
//  - W[o][k]  = sum_i w0[o,i]*w_enc[i,k]   (fp64)
//  - C0[o]    = sum_i b_enc[i]*w0[o,i] + b_rnn[0][o]  (fp64)
//  - split-3 bf16 decomposition of w1 row o into Bw[o][0..767]
// ---------------------------------------------------------------------------
__global__ void prep_kernel(const float* __restrict__ w_enc,
                            const float* __restrict__ b_enc,
                            const float* __restrict__ w_rnn,
                            const float* __restrict__ b_rnn,
                            double* __restrict__ Wd,
                            double* __restrict__ C0d,
                            unsigned short* __restrict__ Bw)
{
    const int o = blockIdx.x;
    const int lane = threadIdx.x;   // 64 threads
    const float4 w0v = *(const float4*)(w_rnn + (size_t)o * 256 + lane * 4);
    double a0 = 0.0, a1 = 0.0, a2 = 0.0, ab = 0.0;
#pragma unroll
    for (int e = 0; e < 4; ++e) {
        const int i = lane * 4 + e;
        const double wv = (double)(((const float*)&w0v)[e]);
        a0 += wv * (double)w_enc[i * 3 + 0];
        a1 += wv * (double)w_enc[i * 3 + 1];
        a2 += wv * (double)w_enc[i * 3 + 2];
        ab += wv * (double)b_enc[i];
    }
    for (int off = 32; off > 0; off >>= 1) {
        a0 += __shfl_down(a0, off, 64);
        a1 += __shfl_down(a1, off, 64);
        a2 += __shfl_down(a2, off, 64);
        ab += __shfl_down(ab, off, 64);
    }
    if (lane == 0) {
        Wd[o * 3 + 0] = a0;
        Wd[o * 3 + 1] = a1;
        Wd[o * 3 + 2] = a2;
        C0d[o] = ab + (double)b_rnn[o];
    }
    // split-3 of w1, exact: f == hi+mid+lo + r, |r| <= 2^-27 |f|
    const float4 w1v = *(const float4*)(w_rnn + 65536 + (size_t)o * 256 + lane * 4);
    ushort4 hi, mi, lo;
#pragma unroll
    for (int e = 0; e < 4; ++e) {
        float f = ((const float*)&w1v)[e];
        unsigned short h = f2bf(f);
        float r1 = f - bf2f(h);
        unsigned short mm = f2bf(r1);
        float r2 = r1 - bf2f(mm);
        unsigned short ll = f2bf(r2);
        ((unsigned short*)&hi)[e] = h;
        ((unsigned short*)&mi)[e] = mm;
        ((unsigned short*)&lo)[e] = ll;
    }
    *(ushort4*)(Bw + (size_t)o * 768 + lane * 4)       = hi;
    *(ushort4*)(Bw + (size_t)o * 768 + 256 + lane * 4) = mi;
    *(ushort4*)(Bw + (size_t)o * 768 + 512 + lane * 4) = lo;
}

// ---------------------------------------------------------------------------
// enc: layer-0 full scan. 2048 blocks x 256 threads. cur0 in fp64 (correctly
// rounded), membrane chain in exact reference fp32 op order. Spikes as
// ballots: s0b u64 index = (t*2048 + n)*4 + wave  (bit j <-> neuron 64w+j)
// ---------------------------------------------------------------------------
__global__ void enc_kernel(const float* __restrict__ inputs,
                           const double* __restrict__ Wd,
                           const double* __restrict__ C0d,
                           unsigned long long* __restrict__ s0b)
{
    const int n = blockIdx.x;
    const int tidx = threadIdx.x;
    const int b = n >> 5, c = n & 31;
    __shared__ float xr[98];
    if (tidx < 96)       xr[tidx + 1] = inputs[((size_t)b * 96 + tidx) * 32 + c];
    else if (tidx == 96) xr[0]  = 0.0f;
    else if (tidx == 97) xr[97] = 0.0f;
    __syncthreads();
    const double W0 = Wd[tidx * 3], W1 = Wd[tidx * 3 + 1], W2 = Wd[tidx * 3 + 2];
    const double c0 = C0d[tidx];
    const int wid = tidx >> 6, lane = tidx & 63;
    float v = 0.0f;
    for (int t = 0; t < 96; ++t) {
        float cur = (float)((double)xr[t] * W0 + (double)xr[t + 1] * W1 +
                            (double)xr[t + 2] * W2 + c0);
        float vv = v + (cur - v) * 0.5f;
        int sp = (vv - 1.0f) >= 0.0f;
        v = sp ? 0.0f : vv;
        unsigned long long bal = __ballot(sp);
        if (lane == 0) s0b[((size_t)t * 2048 + n) * 4 + wid] = bal;
    }
}

// ---------------------------------------------------------------------------
// rnn: layer-1. grid 512 = 128 row-tiles x 4 col-groups; block = 4 waves,
// 16 rows x 64 cols; wave w owns cols [cg*64 + w*16, +16).
// A-fragments shared across waves via double-buffered LDS (expand t+1 while
// computing t). NEW in R3: spike outputs staged in LDS (sbuf, stride 68 to
// break 4-way bank conflicts -> 2-way=free) and drained one step deferred
// with ds_read_b128 + global_store_dwordx4: 256B-contiguous chunks, 1KB per
// store instruction, overlapping step t's MFMAs. One barrier per t.
// MFMA A layout: A[m=lane&15][k=(lane>>4)*8+j]; C/D: col=lane&15,
// row=(lane>>4)*4+reg. Membrane update in exact reference fp32 op order.
// ---------------------------------------------------------------------------
__global__ __launch_bounds__(256, 2) void rnn_kernel(
    const unsigned char* __restrict__ s0b,
    const unsigned short* __restrict__ Bw,
    const float* __restrict__ b_rnn,
    float* __restrict__ out0,
    float* __restrict__ out1)
{
    const int tid  = threadIdx.x;
    const int wid  = tid >> 6, lane = tid & 63;
    const int m    = lane & 15, g = lane >> 4;
    const int g8   = g * 8;
    const int rt   = blockIdx.x >> 2, cg = blockIdx.x & 3;
    const int nw   = rt * 16;                 // block's 16 rows
    const int o0   = cg * 64 + wid * 16;      // this wave's 16 cols

    __shared__ unsigned char ebuf[2][8192];   // 8 A-frags x 1KB, double-buffered
    __shared__ float sbuf[2][16 * 68];        // 16 rows x 64 cols (+4 pad)

    // --- B fragments (loop-invariant): 24 ksteps x 4 VGPRs = 96 VGPRs ---
    short8 bfrag[24];
#pragma unroll
    for (int ks = 0; ks < 24; ++ks)
        bfrag[ks] = *(const short8*)(Bw + (size_t)(o0 + m) * 768 + ks * 32 + g8);
    const float bias = b_rnn[256 + o0 + m];

    // --- out1 rows (direct scatter at t=95, small) ---
    int row_r[4];
#pragma unroll
    for (int r = 0; r < 4; ++r) row_r[r] = nw + g * 4 + r;

    // --- drain mapping: lane covers local row wid*4 + (lane>>4), 4 cols ---
    const int dg = lane >> 4, dm = lane & 15;
    const int drow = wid * 4 + dg;
    const int grow = nw + drow;
    float* dbase = out0 + ((size_t)(grow >> 5) * 96) * 8192
                        + (size_t)(grow & 31) * 256 + cg * 64 + dm * 4;
    const float* dsrc0 = &sbuf[0][drow * 68 + dm * 4];
    const float* dsrc1 = &sbuf[1][drow * 68 + dm * 4];

    // --- mask loader: producer lane handles row nw + m, dwords [2w, 2w+1] ---
    const unsigned char* mbase = s0b + ((size_t)(nw + m)) * 32 + wid * 8;
    #define LOADM(T) (*(const uint2*)(mbase + (size_t)(T) * 65536))

    // preamble: expand t=0 into ebuf[0]; fetch masks for t=1
    {
        uint2 m0 = LOADM(0);
        *(uint4*)(ebuf[0] + (2 * wid) * 1024 + lane * 16)     = expand8((m0.x >> g8) & 0xFFu);
        *(uint4*)(ebuf[0] + (2 * wid + 1) * 1024 + lane * 16) = expand8((m0.y >> g8) & 0xFFu);
    }
    uint2 mB = LOADM(1);

    floatx4 v = {0.f, 0.f, 0.f, 0.f};

    for (int t = 0; t < 96; ++t) {
        const int p = t & 1;
        __syncthreads();   // ebuf[p] + sbuf[1-p] (t-1 spikes) ready
        uint2 mC = LOADM(t + 2 < 96 ? t + 2 : 95);   // prefetch

        // consume A fragments of timestep t
        short8 af[8];
#pragma unroll
        for (int f = 0; f < 8; ++f)
            af[f] = *(const short8*)(ebuf[p] + f * 1024 + lane * 16);

        // drain t-1 spikes: 1KB per wave, 256B-contiguous per 16 lanes
        if (t > 0) {
            float4 sv = *(const float4*)(p ? dsrc0 : dsrc1);
            *(float4*)(dbase + (size_t)(t - 1) * 8192) = sv;
        }

        // produce A fragments of timestep t+1 into ebuf[1-p]
        if (t < 95) {
            *(uint4*)(ebuf[1 - p] + (2 * wid) * 1024 + lane * 16)     = expand8((mB.x >> g8) & 0xFFu);
            *(uint4*)(ebuf[1 - p] + (2 * wid + 1) * 1024 + lane * 16) = expand8((mB.y >> g8) & 0xFFu);
        }

        // GEMM: cur1 tile = spikes @ (w1_hi; w1_mid; w1_lo)
        floatx4 acc = {0.f, 0.f, 0.f, 0.f};
#pragma unroll
        for (int ks = 0; ks < 24; ++ks)
            acc = __builtin_amdgcn_mfma_f32_16x16x32_bf16(af[ks & 7], bfrag[ks], acc, 0, 0, 0);

        // membrane update (exact reference fp32 op order) -> stage in sbuf[p]
#pragma unroll
        for (int r = 0; r < 4; ++r) {
            float cur = acc[r] + bias;
            float vv = v[r];
            vv = vv + (cur - vv) * 0.5f;
            float s = ((vv - 1.0f) >= 0.0f) ? 1.0f : 0.0f;
            v[r] = vv * (1.0f - s);
            sbuf[p][(g * 4 + r) * 68 + wid * 16 + m] = s;
            if (t == 95)
                out1[(size_t)row_r[r] * 256 + o0 + m] = s;
        }
        mB = mC;
    }
    // final drain: t=95 spikes live in sbuf[1]
    __syncthreads();
    {
        float4 sv = *(const float4*)dsrc1;
        *(float4*)(dbase + (size_t)95 * 8192) = sv;
    }
    #undef LOADM
}

// ---------------------------------------------------------------------------
extern "C" void kernel_launch(void* const* d_in, const int* in_sizes, int n_in,
                              void* d_out, int out_size, void* d_ws, size_t ws_size,
                              hipStream_t stream) {
    const float* inputs = (const float*)d_in[0];   // [64,96,32]
    const float* w_enc  = (const float*)d_in[1];   // [256,1,3]
    const float* b_enc  = (const float*)d_in[2];   // [256]
    const float* w_rnn  = (const float*)d_in[3];   // [2,256,256]
    const float* b_rnn  = (const float*)d_in[4];   // [2,256]

    float* out0 = (float*)d_out;                       // [64,96,8192]
    float* out1 = out0 + (size_t)64 * 96 * 8192;       // [64,8192]

    char* ws = (char*)d_ws;
    double*         Wd  = (double*)(ws);               //  768 doubles  [0,6144)
    double*         C0d = (double*)(ws + 6144);        //  256 doubles  [6144,8192)
    unsigned short* Bw  = (unsigned short*)(ws + 8192);// 256*768 u16   [8192,401408)
    char*           s0b = ws + 401408;                 // 6291456 bytes of spike bits

    prep_kernel<<<256, 64, 0, stream>>>(w_enc, b_enc, w_rnn, b_rnn, Wd, C0d, Bw);
    enc_kernel<<<2048, 256, 0, stream>>>(inputs, Wd, C0d, (unsigned long long*)s0b);
    rnn_kernel<<<512, 256, 0, stream>>>((const unsigned char*)s0b, Bw, b_rnn, out0, out1);
}